// Round 1
// 457.345 us; speedup vs baseline: 1.0687x; 1.0687x over previous
//
#include <hip/hip_runtime.h>

#define NQ 2048
#define NB 512    // rows b
#define NX 256    // kernel centers per row
#define NR 1024   // grid resolution
#define KDE_EPS 1e-6f
#define SLOT_ELEMS (NB * NR)            // 524288 floats per bank slot
#define PER_SLOT_V4 (SLOT_ELEMS / 4)    // 131072 = 2^17
#define TOTAL_V4 (128 * PER_SLOT_V4)    // 16777216 float4s in bank/out
// C = log(256) + log(0.1) + log(sqrt(2*pi))
#define LOGC 4.1615308846901885f
#define NORM 0.015583685919813959f      // exp(-LOGC)

#define COPY_BLOCKS 2048
#define EVAL_BLOCKS 2048                // 512 b x 4 chunks of 256 r
#define COPY_ITERS (TOTAL_V4 / (COPY_BLOCKS * 256))  // 32

typedef float f4 __attribute__((ext_vector_type(4)));

// ---------------------------------------------------------------------------
// Single fused kernel. Odd blocks: HBM-bound bank permute-copy (grid-stride,
// nontemporal — single-use streaming data, don't thrash L2/L3). Even blocks:
// per-(b,chunk) eval — stats recomputed per block from LDS-staged inputs
// column (kills the row_stats->grid_eval dependency barrier and turns 1M
// global gathers into ~free 2-way-conflict LDS gathers), then the exp loop.
// Copy (VMEM pipe) and eval (trans/VALU pipe) co-schedule on shared CUs.
// ---------------------------------------------------------------------------
__global__ __launch_bounds__(256) void kde_fused(
    const float* __restrict__ inputs,    // (256, 512)
    const f4*    __restrict__ bank,      // (128, 512, 1024) as float4
    const float* __restrict__ noise,     // (512, 2048)
    const int*   __restrict__ comp_idx,  // (512, 2048)
    const int*   __restrict__ sel,       // (512,)
    const int*   __restrict__ slot_idx_p,
    float* __restrict__ out)             // (128, 512, 1024)
{
    const int tid = threadIdx.x;
    const int bid = blockIdx.x;
    const int slot_idx = *slot_idx_p;

    if (bid & 1) {
        // ------------------- copy role -------------------
        // out[k]=bank[k] (k>=2, k!=slot_idx), out[slot_idx]=bank[0] (= prev).
        // Slots 0/1 (when != slot_idx) are written by eval blocks.
        const int cb = bid >> 1;                 // 0..2047
        f4* o4 = (f4*)out;
        size_t i = (size_t)cb * 256 + tid;
        const size_t stride = (size_t)COPY_BLOCKS * 256;  // 524288 v4
        #pragma unroll 4
        for (int it = 0; it < COPY_ITERS; ++it, i += stride) {
            const int slot = (int)(i >> 17);
            if (slot == slot_idx) {
                const size_t pos = i & (size_t)(PER_SLOT_V4 - 1);
                f4 v = __builtin_nontemporal_load(&bank[pos]);
                __builtin_nontemporal_store(v, &o4[i]);
            } else if (slot >= 2) {
                f4 v = __builtin_nontemporal_load(&bank[i]);
                __builtin_nontemporal_store(v, &o4[i]);
            }
        }
        return;
    }

    // ------------------- eval role -------------------
    const int eb    = bid >> 1;   // 0..2047
    const int b     = eb >> 2;    // 0..511
    const int chunk = eb & 3;     // 0..3

    __shared__ float xsraw[NX];   // inputs column b (raw, for stats gather)
    __shared__ float xs10[NX];    // pre-scaled by 10 (for eval loop)
    __shared__ float red[4][4];

    {
        const float xv = inputs[tid * NB + b];   // tid == center index (NX==256)
        xsraw[tid] = xv;
        xs10[tid]  = xv * 10.0f;
    }
    __syncthreads();

    const int selb = sel[b];

    // ---- per-row min/max of s and y = f_sel(s), gathered from LDS ----
    float mns =  INFINITY, mxs = -INFINITY;
    float mny =  INFINITY, mxy = -INFINITY;
    #pragma unroll
    for (int q = tid; q < NQ; q += 256) {
        const int   idx = comp_idx[b * NQ + q];
        const float nz  = noise[b * NQ + q];
        const float s   = xsraw[idx] + 0.1f * nz;
        mns = fminf(mns, s);
        mxs = fmaxf(mxs, s);
        const float ssafe = (fabsf(s) < KDE_EPS) ? KDE_EPS : s;
        float y;
        switch (selb) {
            case 0:  y = 2.0f * s; break;
            case 1:  y = s - 3.0f; break;
            case 2:  y = 1.0f / ssafe; break;
            case 3:  y = 0.8f * s + 5.0f; break;
            case 4:  y = 1.0f / (1.0f + __expf(-s)); break;
            default: y = fmaxf(s, 0.0f) + log1pf(__expf(-fabsf(s))); break; // softplus
        }
        mny = fminf(mny, y);
        mxy = fmaxf(mxy, y);
    }

    // wave64 butterfly reduce
    #pragma unroll
    for (int off = 32; off > 0; off >>= 1) {
        mns = fminf(mns, __shfl_down(mns, off, 64));
        mxs = fmaxf(mxs, __shfl_down(mxs, off, 64));
        mny = fminf(mny, __shfl_down(mny, off, 64));
        mxy = fmaxf(mxy, __shfl_down(mxy, off, 64));
    }
    const int wave = tid >> 6;
    const int lane = tid & 63;
    if (lane == 0) {
        red[0][wave] = mns; red[1][wave] = mxs;
        red[2][wave] = mny; red[3][wave] = mxy;
    }
    __syncthreads();
    // every thread does the final 4-way reduce itself (no extra barrier)
    mns = fminf(fminf(red[0][0], red[0][1]), fminf(red[0][2], red[0][3]));
    mxs = fmaxf(fmaxf(red[1][0], red[1][1]), fmaxf(red[1][2], red[1][3]));
    mny = fminf(fminf(red[2][0], red[2][1]), fminf(red[2][2], red[2][3]));
    mxy = fmaxf(fmaxf(red[3][0], red[3][1]), fmaxf(red[3][2], red[3][3]));

    // ---- grid points ----
    const int   r  = chunk * 256 + tid;
    const float rr = (float)r / 1023.0f;

    float t0 = mns + (mxs - mns) * rr;
    if (t0 == 0.0f) t0 = 1e-7f;
    float t1 = mny + (mxy - mny) * rr;
    if (t1 == 0.0f) t1 = 1e-7f;

    const float yc01 = fminf(fmaxf(t1, KDE_EPS), 1.0f - KDE_EPS);
    const float ycp  = fmaxf(t1, KDE_EPS);

    float xi, ld;
    switch (selb) {
        case 0:  xi = 0.5f * t1;            ld = -0.6931471805599453f; break;
        case 1:  xi = t1 + 3.0f;            ld = 0.0f;                 break;
        case 2:  xi = 1.0f / t1;            ld = -2.0f * logf(fabsf(t1)); break;
        case 3:  xi = (t1 - 5.0f) * 1.25f;  ld = 0.22314355131420976f; break;
        case 4:  xi = logf(yc01) - log1pf(-yc01);
                 ld = -logf(yc01) - log1pf(-yc01);                     break;
        default: { const float em = expm1f(ycp);
                   xi = logf(em);
                   ld = ycp - xi; }                                     break;
    }

    const float t010 = t0 * 10.0f;
    const float xi10 = xi * 10.0f;

    float acc0 = 0.0f, acc1 = 0.0f;
    #pragma unroll 8
    for (int j = 0; j < NX; ++j) {
        const float xv = xs10[j];
        const float z0 = t010 - xv;
        const float z1 = xi10 - xv;
        acc0 += __expf(-0.5f * z0 * z0);
        acc1 += __expf(-0.5f * z1 * z1);
    }

    const float current     = acc0 * NORM;
    // log-space recombine so acc1==0 with huge ld stays 0 (matches reference),
    // never 0 * inf = NaN.
    const float transformed = __expf(__logf(acc1) + ld - LOGC);

    const size_t o = (size_t)b * NR + r;
    if (slot_idx != 0) out[o] = current;
    if (slot_idx != 1) out[SLOT_ELEMS + o] = transformed;
}

extern "C" void kernel_launch(void* const* d_in, const int* in_sizes, int n_in,
                              void* d_out, int out_size, void* d_ws, size_t ws_size,
                              hipStream_t stream) {
    const float* inputs   = (const float*)d_in[0]; // (256,512)
    const f4*    bank     = (const f4*)d_in[1];    // (128,512,1024)
    const float* noise    = (const float*)d_in[2]; // (512,2048)
    const int*   comp_idx = (const int*)d_in[3];   // (512,2048)
    const int*   sel      = (const int*)d_in[4];   // (512,)
    const int*   slotp    = (const int*)d_in[5];   // scalar
    float* out = (float*)d_out;

    // Interleaved roles: odd blocks copy (HBM pipe), even blocks eval
    // (trans/VALU pipe) — one dispatch, full overlap, no dependency barriers.
    kde_fused<<<COPY_BLOCKS + EVAL_BLOCKS, 256, 0, stream>>>(
        inputs, bank, noise, comp_idx, sel, slotp, out);
}